// Round 12
// baseline (233.662 us; speedup 1.0000x reference)
//
#include <hip/hip_runtime.h>

// GNN collapse: out = A^8 (x · w_in) + sum_l gamma_l A^{8-l} 1 + b_dec
// where A = D_in^-1/2 Adj D_out^-1/2 (scalar field propagation).
//
// Lessons: coop grid.sync 10x worse than small launches (R5). Device-scope
// atomic/scattered-store memory-side ops cost ~28 B HBM traffic each at
// ~28-30 Gops/s (R2/R4/R7/R10/R11) -> minimize op COUNT. Static __shared__
// charged grid-wide (R8). Owner-computes needs block-parallelism AND
// per-thread ILP (R9/R10). Range-partitioned zero-atomic fill scanned every
// edge NR times at 3% occupancy -> 78us (R11). R12: full-node LDS cursors
// (dynamic 100KB) so each edge is scanned once; slot base = per-slice
// prefix from dst histogram; plain ushort stores; zero global atomics.

#define PAD  48   // max in-degree bound; 48 ushorts = 96 B row
#define QSRC 8    // src-histogram slices
#define QD   24   // dst-histogram / fill slices

// ---- prep: src hist + dst hist + coefficient chain, one dispatch ----
// blocks [0,QSRC): src hist slice b. [QSRC,QSRC+QD): dst hist slice b-QSRC.
// last block: coeff chain. coef[0..8]=gamma, coef[16..47]=w_in.
// Hist: full-node packed ushort counters in dynamic LDS (words = (N+1)/2),
// private per-slice output -> plain stores, no global atomics.
__global__ __launch_bounds__(1024) void prep_hist_kernel(
        const int* __restrict__ src, const int* __restrict__ dst,
        const float* __restrict__ W_embed, const float* __restrict__ b_embed,
        const float* __restrict__ Ws, const float* __restrict__ bs,
        const float* __restrict__ W_dec, float* __restrict__ coef,
        unsigned* __restrict__ pu_src, unsigned* __restrict__ pu_dst,
        int words, int N, int E) {
    extern __shared__ unsigned lds[];
    int b = blockIdx.x;
    if (b < QSRC + QD) {
        bool is_src = b < QSRC;
        int q = is_src ? b : b - QSRC;
        int Q = is_src ? QSRC : QD;
        const int* __restrict__ arr = is_src ? src : dst;
        unsigned* __restrict__ pu = is_src ? pu_src : pu_dst;
        for (int i = threadIdx.x; i < words; i += 1024) lds[i] = 0;
        __syncthreads();
        int per = ((E + Q - 1) / Q + 3) & ~3;
        int e0 = q * per;
        int e1 = e0 + per; if (e1 > E) e1 = E;
        if (e0 < e1) {
            const int4* p4 = (const int4*)(arr + e0);
            int m4 = (e1 - e0) >> 2;
            for (int i = threadIdx.x; i < m4; i += 1024) {
                int4 v = p4[i];
                int t;
                t = v.x; if ((unsigned)t < (unsigned)N) atomicAdd(&lds[t >> 1], 1u << ((t & 1) * 16));
                t = v.y; if ((unsigned)t < (unsigned)N) atomicAdd(&lds[t >> 1], 1u << ((t & 1) * 16));
                t = v.z; if ((unsigned)t < (unsigned)N) atomicAdd(&lds[t >> 1], 1u << ((t & 1) * 16));
                t = v.w; if ((unsigned)t < (unsigned)N) atomicAdd(&lds[t >> 1], 1u << ((t & 1) * 16));
            }
            for (int e = e0 + (m4 << 2) + threadIdx.x; e < e1; e += 1024) {
                int t = arr[e];
                if ((unsigned)t < (unsigned)N) atomicAdd(&lds[t >> 1], 1u << ((t & 1) * 16));
            }
        }
        __syncthreads();
        unsigned* outp = pu + (size_t)q * words;
        for (int i = threadIdx.x; i < words; i += 1024) outp[i] = lds[i];
    } else {
        __shared__ float shv[64];
        __shared__ float shg[9];
        int i = threadIdx.x;
        if (i < 64) shv[i] = W_dec[i];
        __syncthreads();
        for (int l = 7; l >= 0; --l) {
            float a = 0.f;
            if (i < 64) {
                float p = bs[l * 64 + i] * shv[i];
                for (int d = 32; d; d >>= 1) p += __shfl_xor(p, d);
                if (i == 0) shg[l + 1] = p;
                const float* Wrow = Ws + l * 4096 + i * 64;
                for (int j = 0; j < 64; ++j) a += Wrow[j] * shv[j];
            }
            __syncthreads();
            if (i < 64) shv[i] = a;
            __syncthreads();
        }
        if (i < 64) {
            float p = b_embed[i] * shv[i];
            for (int d = 32; d; d >>= 1) p += __shfl_xor(p, d);
            if (i == 0) shg[0] = p;
        }
        __syncthreads();
        if (i < 32) {
            float a = 0.f;
            const float* Wr = W_embed + i * 64;
            for (int j = 0; j < 64; ++j) a += Wr[j] * shv[j];
            coef[16 + i] = a;
        }
        if (i < 9) coef[i] = shg[i];
    }
}

// ---- fill: zero global atomics, each edge scanned ONCE ----
// Block q: LDS cursors for ALL nodes, init = prefix sum_{q'<q} pu_dst[q']
// (disjoint slot sub-ranges across blocks). Scan slice q: LDS returning
// atomic -> slot, plain ushort store. Block QD-1's final cursors = exact
// in-degrees -> writes packed cnt_in.
__global__ __launch_bounds__(1024) void fill_kernel(
        const int* __restrict__ src, const int* __restrict__ dst,
        const unsigned* __restrict__ pu_dst, unsigned* __restrict__ cnt_in,
        unsigned short* __restrict__ csr, int words, int N, int E) {
    extern __shared__ unsigned cur[];
    int q = blockIdx.x;
    for (int j = threadIdx.x; j < words; j += 1024) {
        unsigned s = 0;
        for (int qq = 0; qq < q; ++qq) s += pu_dst[(size_t)qq * words + j];
        cur[j] = s;   // packed add safe: per-half counts << 2^16
    }
    __syncthreads();
    int per = ((E + QD - 1) / QD + 3) & ~3;
    int e0 = q * per;
    int e1 = e0 + per; if (e1 > E) e1 = E;
    if (e0 < e1) {
        const int4* s4p = (const int4*)(src + e0);
        const int4* d4p = (const int4*)(dst + e0);
        int m4 = (e1 - e0) >> 2;
        for (int i = threadIdx.x; i < m4; i += 1024) {
            int4 sv = s4p[i];
            int4 dv = d4p[i];
            int t, sh, p; unsigned old;
            t = dv.x;
            if ((unsigned)t < (unsigned)N) {
                sh = (t & 1) * 16; old = atomicAdd(&cur[t >> 1], 1u << sh);
                p = (old >> sh) & 0xFFFF;
                if (p < PAD) csr[(size_t)t * PAD + p] = (unsigned short)sv.x;
            }
            t = dv.y;
            if ((unsigned)t < (unsigned)N) {
                sh = (t & 1) * 16; old = atomicAdd(&cur[t >> 1], 1u << sh);
                p = (old >> sh) & 0xFFFF;
                if (p < PAD) csr[(size_t)t * PAD + p] = (unsigned short)sv.y;
            }
            t = dv.z;
            if ((unsigned)t < (unsigned)N) {
                sh = (t & 1) * 16; old = atomicAdd(&cur[t >> 1], 1u << sh);
                p = (old >> sh) & 0xFFFF;
                if (p < PAD) csr[(size_t)t * PAD + p] = (unsigned short)sv.z;
            }
            t = dv.w;
            if ((unsigned)t < (unsigned)N) {
                sh = (t & 1) * 16; old = atomicAdd(&cur[t >> 1], 1u << sh);
                p = (old >> sh) & 0xFFFF;
                if (p < PAD) csr[(size_t)t * PAD + p] = (unsigned short)sv.w;
            }
        }
        for (int e = e0 + (m4 << 2) + threadIdx.x; e < e1; e += 1024) {
            int t = dst[e];
            if ((unsigned)t < (unsigned)N) {
                int sh = (t & 1) * 16;
                unsigned old = atomicAdd(&cur[t >> 1], 1u << sh);
                int p = (old >> sh) & 0xFFFF;
                if (p < PAD) csr[(size_t)t * PAD + p] = (unsigned short)src[e];
            }
        }
    }
    __syncthreads();
    if (q == QD - 1)
        for (int j = threadIdx.x; j < words; j += 1024) cnt_in[j] = cur[j];
}

// ---- z0 + inv precompute (deg_out = sum of QSRC packed partials) ----
__global__ __launch_bounds__(256) void z0_kernel(
        const float* __restrict__ x, const float* __restrict__ coef,
        const unsigned* __restrict__ pu_src, const unsigned* __restrict__ cnt_in,
        float* __restrict__ inv_out, float* __restrict__ inv_in,
        float* __restrict__ ts0, int words, int N) {
    __shared__ float w[33];
    if (threadIdx.x < 32) w[threadIdx.x] = coef[16 + threadIdx.x];
    if (threadIdx.x == 32) w[32] = coef[0];
    __syncthreads();
    int n = blockIdx.x * 256 + threadIdx.x;
    if (n >= N) return;
    const float4* xr = (const float4*)(x + (size_t)n * 32);
    float acc = 0.f;
#pragma unroll
    for (int q = 0; q < 8; ++q) {
        float4 vv = xr[q];
        acc += vv.x * w[q * 4] + vv.y * w[q * 4 + 1] + vv.z * w[q * 4 + 2] + vv.w * w[q * 4 + 3];
    }
    int j = n >> 1, sh = (n & 1) * 16;
    int co = 0;
#pragma unroll
    for (int q = 0; q < QSRC; ++q)
        co += (pu_src[(size_t)q * words + j] >> sh) & 0xFFFF;
    if (co < 1) co = 1;
    int ci = (cnt_in[j] >> sh) & 0xFFFF;
    if (ci < 1) ci = 1;
    float io = rsqrtf((float)co);
    inv_out[n] = io;
    inv_in[n] = rsqrtf((float)ci);
    ts0[n] = io * (acc + w[32]);
}

// ---- 4-lane-per-node gather: each sub-lane does <=4 entries per 16-stripe ----
__device__ __forceinline__ float quad_gather(const unsigned short* __restrict__ row,
                                             const float* __restrict__ ta,
                                             int c, int sub) {
    float acc = 0.f;
#pragma unroll
    for (int t = 0; t < PAD / 16; ++t) {
        int eb = sub * 4 + 16 * t;
        if (eb < c) {
            uint2 v = *(const uint2*)(row + eb);   // 4 ushorts, 8B-aligned
            unsigned i0 = v.x & 0xFFFF, i1 = v.x >> 16;
            unsigned i2 = v.y & 0xFFFF, i3 = v.y >> 16;
            acc += ta[i0];
            if (eb + 1 < c) acc += ta[i1];
            if (eb + 2 < c) acc += ta[i2];
            if (eb + 3 < c) acc += ta[i3];
        }
    }
    return acc;
}

// ts_out[n] = inv_out[n] * (inv_in[n] * gather + coef[k]);  4 threads per node
__global__ __launch_bounds__(256) void prop_kernel(
        const float* __restrict__ ts_in, float* __restrict__ ts_out,
        const float* __restrict__ inv_out, const float* __restrict__ inv_in,
        const unsigned* __restrict__ cnt_in, const unsigned short* __restrict__ csr,
        const float* __restrict__ coef, int k, int N) {
    int tid = blockIdx.x * 256 + threadIdx.x;
    int n = tid >> 2, sub = tid & 3;
    if (n >= N) return;
    int c = (cnt_in[n >> 1] >> ((n & 1) * 16)) & 0xFFFF;
    if (c > PAD) c = PAD;
    float acc = quad_gather(csr + (size_t)n * PAD, ts_in, c, sub);
    acc += __shfl_xor(acc, 1);
    acc += __shfl_xor(acc, 2);
    if (sub == 0) ts_out[n] = inv_out[n] * (inv_in[n] * acc + coef[k]);
}

// out[n] = inv_in[n] * gather + coef[8] + b_dec;  4 threads per node
__global__ __launch_bounds__(256) void final_kernel(
        const float* __restrict__ ts_in, float* __restrict__ out,
        const float* __restrict__ inv_in, const unsigned* __restrict__ cnt_in,
        const unsigned short* __restrict__ csr, const float* __restrict__ coef,
        const float* __restrict__ b_dec, int N) {
    int tid = blockIdx.x * 256 + threadIdx.x;
    int n = tid >> 2, sub = tid & 3;
    if (n >= N) return;
    int c = (cnt_in[n >> 1] >> ((n & 1) * 16)) & 0xFFFF;
    if (c > PAD) c = PAD;
    float acc = quad_gather(csr + (size_t)n * PAD, ts_in, c, sub);
    acc += __shfl_xor(acc, 1);
    acc += __shfl_xor(acc, 2);
    if (sub == 0) out[n] = inv_in[n] * acc + coef[8] + b_dec[0];
}

// ---- int-id fallback (N > 65536): R7 structure, int CSR, atomic counters ----
__global__ __launch_bounds__(256) void prep_kernel_i(
        const float* __restrict__ W_embed, const float* __restrict__ b_embed,
        const float* __restrict__ Ws, const float* __restrict__ bs,
        const float* __restrict__ W_dec, float* __restrict__ coef,
        int* __restrict__ cnt, int NZ) {
    int g = blockIdx.x * 256 + threadIdx.x;
    for (int i = g; i < NZ; i += gridDim.x * 256) cnt[i] = 0;
    if (blockIdx.x == 0) {
        __shared__ float shv[64];
        __shared__ float shg[9];
        int i = threadIdx.x;
        if (i < 64) shv[i] = W_dec[i];
        __syncthreads();
        for (int l = 7; l >= 0; --l) {
            float a = 0.f;
            if (i < 64) {
                float p = bs[l * 64 + i] * shv[i];
                for (int d = 32; d; d >>= 1) p += __shfl_xor(p, d);
                if (i == 0) shg[l + 1] = p;
                const float* Wrow = Ws + l * 4096 + i * 64;
                for (int j = 0; j < 64; ++j) a += Wrow[j] * shv[j];
            }
            __syncthreads();
            if (i < 64) shv[i] = a;
            __syncthreads();
        }
        if (i < 64) {
            float p = b_embed[i] * shv[i];
            for (int d = 32; d; d >>= 1) p += __shfl_xor(p, d);
            if (i == 0) shg[0] = p;
        }
        __syncthreads();
        if (i < 32) {
            float a = 0.f;
            const float* Wr = W_embed + i * 64;
            for (int j = 0; j < 64; ++j) a += Wr[j] * shv[j];
            coef[16 + i] = a;
        }
        if (i < 9) coef[i] = shg[i];
    }
}

__global__ __launch_bounds__(256) void fill_kernel_i(
        const int* __restrict__ src, const int* __restrict__ dst,
        int* __restrict__ cnt_out, int* __restrict__ cursor,
        int* __restrict__ csr, int E) {
    int i = blockIdx.x * 256 + threadIdx.x;
    if (i >= E) return;
    int s = src[i], d = dst[i];
    atomicAdd(&cnt_out[s], 1);
    int p = atomicAdd(&cursor[d], 1);
    if (p < PAD) csr[(size_t)d * PAD + p] = s;
}

__global__ __launch_bounds__(256) void z0_kernel_i(
        const float* __restrict__ x, const float* __restrict__ coef,
        const int* __restrict__ cnt_out, const int* __restrict__ cursor,
        float* __restrict__ inv_out, float* __restrict__ inv_in,
        float* __restrict__ ts0, int N) {
    __shared__ float w[33];
    if (threadIdx.x < 32) w[threadIdx.x] = coef[16 + threadIdx.x];
    if (threadIdx.x == 32) w[32] = coef[0];
    __syncthreads();
    int n = blockIdx.x * 256 + threadIdx.x;
    if (n >= N) return;
    const float4* xr = (const float4*)(x + (size_t)n * 32);
    float acc = 0.f;
#pragma unroll
    for (int q = 0; q < 8; ++q) {
        float4 vv = xr[q];
        acc += vv.x * w[q * 4] + vv.y * w[q * 4 + 1] + vv.z * w[q * 4 + 2] + vv.w * w[q * 4 + 3];
    }
    int co = cnt_out[n]; if (co < 1) co = 1;
    int ci = cursor[n];  if (ci < 1) ci = 1;
    float io = rsqrtf((float)co);
    inv_out[n] = io;
    inv_in[n] = rsqrtf((float)ci);
    ts0[n] = io * (acc + w[32]);
}

__global__ __launch_bounds__(256) void prop_kernel_i(
        const float* __restrict__ ts_in, float* __restrict__ ts_out,
        const float* __restrict__ inv_out, const float* __restrict__ inv_in,
        const int* __restrict__ cursor, const int* __restrict__ csr,
        const float* __restrict__ coef, int k, int N) {
    int n = blockIdx.x * 256 + threadIdx.x;
    if (n >= N) return;
    int c = cursor[n]; if (c > PAD) c = PAD;
    const int* row = csr + (size_t)n * PAD;
    float acc = 0.f;
    for (int e = 0; e < c; ++e) acc += ts_in[row[e]];
    ts_out[n] = inv_out[n] * (inv_in[n] * acc + coef[k]);
}

__global__ __launch_bounds__(256) void final_kernel_i(
        const float* __restrict__ ts_in, float* __restrict__ out,
        const float* __restrict__ inv_in, const int* __restrict__ cursor,
        const int* __restrict__ csr, const float* __restrict__ coef,
        const float* __restrict__ b_dec, int N) {
    int n = blockIdx.x * 256 + threadIdx.x;
    if (n >= N) return;
    int c = cursor[n]; if (c > PAD) c = PAD;
    const int* row = csr + (size_t)n * PAD;
    float acc = 0.f;
    for (int e = 0; e < c; ++e) acc += ts_in[row[e]];
    out[n] = inv_in[n] * acc + coef[8] + b_dec[0];
}

extern "C" void kernel_launch(void* const* d_in, const int* in_sizes, int n_in,
                              void* d_out, int out_size, void* d_ws, size_t ws_size,
                              hipStream_t stream) {
    const float* x       = (const float*)d_in[0];
    const int*   src     = (const int*)d_in[1];
    const int*   dst     = (const int*)d_in[2];
    const float* W_embed = (const float*)d_in[3];
    const float* b_embed = (const float*)d_in[4];
    const float* Ws      = (const float*)d_in[5];
    const float* bs      = (const float*)d_in[6];
    const float* W_dec   = (const float*)d_in[7];
    const float* b_dec   = (const float*)d_in[8];
    float* out = (float*)d_out;
    int N = in_sizes[0] / 32;
    int E = in_sizes[1];

    int nbl  = (N + 255) / 256;
    int nbl4 = (4 * N + 255) / 256;
    int ebl  = (E + 255) / 256;
    char* w = (char*)d_ws;

    if (N <= 65536) {
        int words = (N + 1) >> 1;
        size_t shb = (size_t)words * 4;   // dynamic LDS bytes (<=128 KB)
        size_t o = 0;
        unsigned* pu_src = (unsigned*)(w + o); o += (size_t)QSRC * words * 4; o = (o + 255) & ~(size_t)255;
        unsigned* pu_dst = (unsigned*)(w + o); o += (size_t)QD * words * 4;   o = (o + 255) & ~(size_t)255;
        unsigned* cnt_in = (unsigned*)(w + o); o += (size_t)words * 4;        o = (o + 255) & ~(size_t)255;
        float* inv_out = (float*)(w + o); o += (size_t)N * 4; o = (o + 255) & ~(size_t)255;
        float* inv_in  = (float*)(w + o); o += (size_t)N * 4; o = (o + 255) & ~(size_t)255;
        float* coef    = (float*)(w + o); o += 256;
        float* tsA     = (float*)(w + o); o += (size_t)N * 4; o = (o + 255) & ~(size_t)255;
        float* tsB     = (float*)(w + o); o += (size_t)N * 4; o = (o + 255) & ~(size_t)255;
        unsigned short* csr = (unsigned short*)(w + o);

        prep_hist_kernel<<<QSRC + QD + 1, 1024, shb, stream>>>(
            src, dst, W_embed, b_embed, Ws, bs, W_dec, coef, pu_src, pu_dst, words, N, E);
        fill_kernel<<<QD, 1024, shb, stream>>>(src, dst, pu_dst, cnt_in, csr, words, N, E);
        z0_kernel<<<nbl, 256, 0, stream>>>(x, coef, pu_src, cnt_in, inv_out, inv_in, tsA, words, N);
        float* ta = tsA; float* tb = tsB;
        for (int k = 1; k <= 7; ++k) {
            prop_kernel<<<nbl4, 256, 0, stream>>>(ta, tb, inv_out, inv_in, cnt_in, csr, coef, k, N);
            float* tmp = ta; ta = tb; tb = tmp;
        }
        final_kernel<<<nbl4, 256, 0, stream>>>(ta, out, inv_in, cnt_in, csr, coef, b_dec, N);
    } else {
        size_t o = 0;
        int* cursor  = (int*)(w + o); o += (size_t)N * 4;
        int* cnt_out = (int*)(w + o); o += (size_t)N * 4;
        o = (o + 255) & ~(size_t)255;
        float* inv_out = (float*)(w + o); o += (size_t)N * 4; o = (o + 255) & ~(size_t)255;
        float* inv_in  = (float*)(w + o); o += (size_t)N * 4; o = (o + 255) & ~(size_t)255;
        float* coef    = (float*)(w + o); o += 256;
        float* tsA     = (float*)(w + o); o += (size_t)N * 4; o = (o + 255) & ~(size_t)255;
        float* tsB     = (float*)(w + o); o += (size_t)N * 4; o = (o + 255) & ~(size_t)255;
        int* csr = (int*)(w + o);

        prep_kernel_i<<<128, 256, 0, stream>>>(W_embed, b_embed, Ws, bs, W_dec, coef, cursor, 2 * N);
        fill_kernel_i<<<ebl, 256, 0, stream>>>(src, dst, cnt_out, cursor, csr, E);
        z0_kernel_i<<<nbl, 256, 0, stream>>>(x, coef, cnt_out, cursor, inv_out, inv_in, tsA, N);
        float* ta = tsA; float* tb = tsB;
        for (int k = 1; k <= 7; ++k) {
            prop_kernel_i<<<nbl, 256, 0, stream>>>(ta, tb, inv_out, inv_in, cursor, csr, coef, k, N);
            float* tmp = ta; ta = tb; tb = tmp;
        }
        final_kernel_i<<<nbl, 256, 0, stream>>>(ta, out, inv_in, cursor, csr, coef, b_dec, N);
    }
}

// Round 13
// 119.418 us; speedup vs baseline: 1.9567x; 1.9567x over previous
//
#include <hip/hip_runtime.h>

// GNN collapse: out = A^8 (x · w_in) + sum_l gamma_l A^{8-l} 1 + b_dec
// where A = D_in^-1/2 Adj D_out^-1/2 (scalar field propagation).
//
// Lessons: coop grid.sync 10x worse than small launches (R5). Device-scope
// atomic/scattered-store memory-side ops cost ~28 B HBM traffic each at
// ~30 Gops/s regardless of occupancy>~25% (R2/R4/R7/R10) -> minimize op
// COUNT. Static __shared__ charged grid-wide (R8). Owner-computes needs
// block-parallelism AND per-thread ILP (R9/R10). Zero-global-atomic fills
// lose: range-split scans edges NRx (R11), full-node LDS cursors kill
// occupancy (R12). CSR build floor = 1 atomic + 1 store per edge (R10).

#define PAD 48     // max in-degree bound; 48 ushorts = 96 B row
#define HS 32      // histogram slices
#define HR 4       // histogram node ranges (16384 nodes, 32 KB LDS each)
#define HBLK (HS * HR)

// ---- prep + src-histogram: one dispatch ----
// blocks [0,HBLK): owner-computes src histogram. Block b: slice q=b>>2,
//   range r=b&3 (nodes [r*16384,(r+1)*16384)). LDS = 8192 uints = 16384
//   packed ushort counters. pu[b*8192 + i] privately owned -> plain stores.
// block HBLK: coefficient chain. blocks > HBLK: zero cursor.
// coef[0..8] = gamma_0..gamma_8, coef[16..47] = w_in[0..31]
__global__ __launch_bounds__(256) void prep_hist_kernel(
        const int* __restrict__ src,
        const float* __restrict__ W_embed, const float* __restrict__ b_embed,
        const float* __restrict__ Ws, const float* __restrict__ bs,
        const float* __restrict__ W_dec, float* __restrict__ coef,
        int* __restrict__ cursor, unsigned* __restrict__ pu, int N, int E) {
    __shared__ unsigned lds[8192];   // 32 KB
    int b = blockIdx.x;
    if (b < HBLK) {
        int q = b >> 2, r = b & 3;
        for (int i = threadIdx.x; i < 8192; i += 256) lds[i] = 0;
        __syncthreads();
        int base = r << 14;
        int per = ((E + HS - 1) / HS + 3) & ~3;      // slice length, 4-aligned
        int e0 = q * per;
        int e1 = e0 + per; if (e1 > E) e1 = E;
        if (e0 < e1) {
            const int4* p4 = (const int4*)(src + e0);
            int m4 = (e1 - e0) >> 2;
            for (int i = threadIdx.x; i < m4; i += 256) {
                int4 v = p4[i];
                int t;
                t = v.x - base; if ((unsigned)t < 16384u) atomicAdd(&lds[t >> 1], 1u << ((t & 1) * 16));
                t = v.y - base; if ((unsigned)t < 16384u) atomicAdd(&lds[t >> 1], 1u << ((t & 1) * 16));
                t = v.z - base; if ((unsigned)t < 16384u) atomicAdd(&lds[t >> 1], 1u << ((t & 1) * 16));
                t = v.w - base; if ((unsigned)t < 16384u) atomicAdd(&lds[t >> 1], 1u << ((t & 1) * 16));
            }
            for (int e = e0 + (m4 << 2) + threadIdx.x; e < e1; e += 256) {
                int t = src[e] - base;
                if ((unsigned)t < 16384u) atomicAdd(&lds[t >> 1], 1u << ((t & 1) * 16));
            }
        }
        __syncthreads();
        unsigned* outp = pu + (size_t)b * 8192;
        for (int i = threadIdx.x; i < 8192; i += 256) outp[i] = lds[i];
    } else if (b == HBLK) {
        __shared__ float shv[64];
        __shared__ float shg[9];
        int i = threadIdx.x;
        if (i < 64) shv[i] = W_dec[i];
        __syncthreads();
        for (int l = 7; l >= 0; --l) {
            float a = 0.f;
            if (i < 64) {
                float p = bs[l * 64 + i] * shv[i];
                for (int d = 32; d; d >>= 1) p += __shfl_xor(p, d);
                if (i == 0) shg[l + 1] = p;
                const float* Wrow = Ws + l * 4096 + i * 64;
                for (int j = 0; j < 64; ++j) a += Wrow[j] * shv[j];
            }
            __syncthreads();
            if (i < 64) shv[i] = a;
            __syncthreads();
        }
        if (i < 64) {
            float p = b_embed[i] * shv[i];
            for (int d = 32; d; d >>= 1) p += __shfl_xor(p, d);
            if (i == 0) shg[0] = p;
        }
        __syncthreads();
        if (i < 32) {
            float a = 0.f;
            const float* Wr = W_embed + i * 64;
            for (int j = 0; j < 64; ++j) a += Wr[j] * shv[j];
            coef[16 + i] = a;
        }
        if (i < 9) coef[i] = shg[i];
    } else {
        int g = (b - HBLK - 1) * 256 + threadIdx.x;
        int stride = (gridDim.x - HBLK - 1) * 256;
        for (int i = g; i < N; i += stride) cursor[i] = 0;
    }
}

// ---- fill: 1 edge/thread, no LDS; returning atomicAdd on cursor[dst]
//      doubles as in-degree count and csr slot ----
__global__ __launch_bounds__(256) void fill_kernel(
        const int* __restrict__ src, const int* __restrict__ dst,
        int* __restrict__ cursor, unsigned short* __restrict__ csr, int E) {
    int i = blockIdx.x * 256 + threadIdx.x;
    if (i >= E) return;
    int s = src[i], d = dst[i];
    int p = atomicAdd(&cursor[d], 1);
    if (p < PAD) csr[(size_t)d * PAD + p] = (unsigned short)s;
}

// ---- z0 + inv precompute (deg_out = sum of HS packed partials) ----
__global__ __launch_bounds__(256) void z0_kernel(
        const float* __restrict__ x, const float* __restrict__ coef,
        const unsigned* __restrict__ pu, const int* __restrict__ cursor,
        float* __restrict__ inv_out, float* __restrict__ inv_in,
        float* __restrict__ ts0, int N) {
    __shared__ float w[33];
    if (threadIdx.x < 32) w[threadIdx.x] = coef[16 + threadIdx.x];
    if (threadIdx.x == 32) w[32] = coef[0];
    __syncthreads();
    int n = blockIdx.x * 256 + threadIdx.x;
    if (n >= N) return;
    const float4* xr = (const float4*)(x + (size_t)n * 32);
    float acc = 0.f;
#pragma unroll
    for (int q = 0; q < 8; ++q) {
        float4 vv = xr[q];
        acc += vv.x * w[q * 4] + vv.y * w[q * 4 + 1] + vv.z * w[q * 4 + 2] + vv.w * w[q * 4 + 3];
    }
    int r = n >> 14, j = (n & 16383) >> 1, sh = (n & 1) * 16;
    int co = 0;
#pragma unroll
    for (int q = 0; q < HS; ++q)
        co += (pu[(size_t)((q << 2) | r) * 8192 + j] >> sh) & 0xFFFF;
    if (co < 1) co = 1;
    int ci = cursor[n]; if (ci < 1) ci = 1;
    float io = rsqrtf((float)co);
    inv_out[n] = io;
    inv_in[n] = rsqrtf((float)ci);
    ts0[n] = io * (acc + w[32]);
}

// ---- 4-lane-per-node gather, branchless index loads ----
// All 3 uint2 index loads issued up-front (rows PAD-padded; garbage slots
// read valid workspace memory and are predicated off at the accumulate).
__device__ __forceinline__ float quad_gather(const unsigned short* __restrict__ row,
                                             const float* __restrict__ ta,
                                             int c, int sub) {
    int e0 = sub * 4;
    uint2 v0 = *(const uint2*)(row + e0);        // slots e0..e0+3
    uint2 v1 = *(const uint2*)(row + e0 + 16);   // slots e0+16..
    uint2 v2 = *(const uint2*)(row + e0 + 32);   // slots e0+32..
    float acc = 0.f;
#define ACC4(v, eb)                                                        \
    {                                                                      \
        unsigned a0 = (v).x & 0xFFFFu, a1 = (v).x >> 16;                   \
        unsigned a2 = (v).y & 0xFFFFu, a3 = (v).y >> 16;                   \
        if ((eb) + 0 < c) acc += ta[a0];                                   \
        if ((eb) + 1 < c) acc += ta[a1];                                   \
        if ((eb) + 2 < c) acc += ta[a2];                                   \
        if ((eb) + 3 < c) acc += ta[a3];                                   \
    }
    ACC4(v0, e0)
    ACC4(v1, e0 + 16)
    ACC4(v2, e0 + 32)
#undef ACC4
    return acc;
}

// ts_out[n] = inv_out[n] * (inv_in[n] * gather + coef[k]);  4 threads per node
__global__ __launch_bounds__(256) void prop_kernel(
        const float* __restrict__ ts_in, float* __restrict__ ts_out,
        const float* __restrict__ inv_out, const float* __restrict__ inv_in,
        const int* __restrict__ cursor, const unsigned short* __restrict__ csr,
        const float* __restrict__ coef, int k, int N) {
    int tid = blockIdx.x * 256 + threadIdx.x;
    int n = tid >> 2, sub = tid & 3;
    if (n >= N) return;
    int c = cursor[n]; if (c > PAD) c = PAD;
    float acc = quad_gather(csr + (size_t)n * PAD, ts_in, c, sub);
    acc += __shfl_xor(acc, 1);
    acc += __shfl_xor(acc, 2);
    if (sub == 0) ts_out[n] = inv_out[n] * (inv_in[n] * acc + coef[k]);
}

// out[n] = inv_in[n] * gather + coef[8] + b_dec;  4 threads per node
__global__ __launch_bounds__(256) void final_kernel(
        const float* __restrict__ ts_in, float* __restrict__ out,
        const float* __restrict__ inv_in, const int* __restrict__ cursor,
        const unsigned short* __restrict__ csr, const float* __restrict__ coef,
        const float* __restrict__ b_dec, int N) {
    int tid = blockIdx.x * 256 + threadIdx.x;
    int n = tid >> 2, sub = tid & 3;
    if (n >= N) return;
    int c = cursor[n]; if (c > PAD) c = PAD;
    float acc = quad_gather(csr + (size_t)n * PAD, ts_in, c, sub);
    acc += __shfl_xor(acc, 1);
    acc += __shfl_xor(acc, 2);
    if (sub == 0) out[n] = inv_in[n] * acc + coef[8] + b_dec[0];
}

// ---- int-id fallback (N > 65536): R7 structure, int CSR, atomic counters ----
__global__ __launch_bounds__(256) void prep_kernel_i(
        const float* __restrict__ W_embed, const float* __restrict__ b_embed,
        const float* __restrict__ Ws, const float* __restrict__ bs,
        const float* __restrict__ W_dec, float* __restrict__ coef,
        int* __restrict__ cnt, int NZ) {
    int g = blockIdx.x * 256 + threadIdx.x;
    for (int i = g; i < NZ; i += gridDim.x * 256) cnt[i] = 0;
    if (blockIdx.x == 0) {
        __shared__ float shv[64];
        __shared__ float shg[9];
        int i = threadIdx.x;
        if (i < 64) shv[i] = W_dec[i];
        __syncthreads();
        for (int l = 7; l >= 0; --l) {
            float a = 0.f;
            if (i < 64) {
                float p = bs[l * 64 + i] * shv[i];
                for (int d = 32; d; d >>= 1) p += __shfl_xor(p, d);
                if (i == 0) shg[l + 1] = p;
                const float* Wrow = Ws + l * 4096 + i * 64;
                for (int j = 0; j < 64; ++j) a += Wrow[j] * shv[j];
            }
            __syncthreads();
            if (i < 64) shv[i] = a;
            __syncthreads();
        }
        if (i < 64) {
            float p = b_embed[i] * shv[i];
            for (int d = 32; d; d >>= 1) p += __shfl_xor(p, d);
            if (i == 0) shg[0] = p;
        }
        __syncthreads();
        if (i < 32) {
            float a = 0.f;
            const float* Wr = W_embed + i * 64;
            for (int j = 0; j < 64; ++j) a += Wr[j] * shv[j];
            coef[16 + i] = a;
        }
        if (i < 9) coef[i] = shg[i];
    }
}

__global__ __launch_bounds__(256) void fill_kernel_i(
        const int* __restrict__ src, const int* __restrict__ dst,
        int* __restrict__ cnt_out, int* __restrict__ cursor,
        int* __restrict__ csr, int E) {
    int i = blockIdx.x * 256 + threadIdx.x;
    if (i >= E) return;
    int s = src[i], d = dst[i];
    atomicAdd(&cnt_out[s], 1);
    int p = atomicAdd(&cursor[d], 1);
    if (p < PAD) csr[(size_t)d * PAD + p] = s;
}

__global__ __launch_bounds__(256) void z0_kernel_i(
        const float* __restrict__ x, const float* __restrict__ coef,
        const int* __restrict__ cnt_out, const int* __restrict__ cursor,
        float* __restrict__ inv_out, float* __restrict__ inv_in,
        float* __restrict__ ts0, int N) {
    __shared__ float w[33];
    if (threadIdx.x < 32) w[threadIdx.x] = coef[16 + threadIdx.x];
    if (threadIdx.x == 32) w[32] = coef[0];
    __syncthreads();
    int n = blockIdx.x * 256 + threadIdx.x;
    if (n >= N) return;
    const float4* xr = (const float4*)(x + (size_t)n * 32);
    float acc = 0.f;
#pragma unroll
    for (int q = 0; q < 8; ++q) {
        float4 vv = xr[q];
        acc += vv.x * w[q * 4] + vv.y * w[q * 4 + 1] + vv.z * w[q * 4 + 2] + vv.w * w[q * 4 + 3];
    }
    int co = cnt_out[n]; if (co < 1) co = 1;
    int ci = cursor[n];  if (ci < 1) ci = 1;
    float io = rsqrtf((float)co);
    inv_out[n] = io;
    inv_in[n] = rsqrtf((float)ci);
    ts0[n] = io * (acc + w[32]);
}

__global__ __launch_bounds__(256) void prop_kernel_i(
        const float* __restrict__ ts_in, float* __restrict__ ts_out,
        const float* __restrict__ inv_out, const float* __restrict__ inv_in,
        const int* __restrict__ cursor, const int* __restrict__ csr,
        const float* __restrict__ coef, int k, int N) {
    int n = blockIdx.x * 256 + threadIdx.x;
    if (n >= N) return;
    int c = cursor[n]; if (c > PAD) c = PAD;
    const int* row = csr + (size_t)n * PAD;
    float acc = 0.f;
    for (int e = 0; e < c; ++e) acc += ts_in[row[e]];
    ts_out[n] = inv_out[n] * (inv_in[n] * acc + coef[k]);
}

__global__ __launch_bounds__(256) void final_kernel_i(
        const float* __restrict__ ts_in, float* __restrict__ out,
        const float* __restrict__ inv_in, const int* __restrict__ cursor,
        const int* __restrict__ csr, const float* __restrict__ coef,
        const float* __restrict__ b_dec, int N) {
    int n = blockIdx.x * 256 + threadIdx.x;
    if (n >= N) return;
    int c = cursor[n]; if (c > PAD) c = PAD;
    const int* row = csr + (size_t)n * PAD;
    float acc = 0.f;
    for (int e = 0; e < c; ++e) acc += ts_in[row[e]];
    out[n] = inv_in[n] * acc + coef[8] + b_dec[0];
}

extern "C" void kernel_launch(void* const* d_in, const int* in_sizes, int n_in,
                              void* d_out, int out_size, void* d_ws, size_t ws_size,
                              hipStream_t stream) {
    const float* x       = (const float*)d_in[0];
    const int*   src     = (const int*)d_in[1];
    const int*   dst     = (const int*)d_in[2];
    const float* W_embed = (const float*)d_in[3];
    const float* b_embed = (const float*)d_in[4];
    const float* Ws      = (const float*)d_in[5];
    const float* bs      = (const float*)d_in[6];
    const float* W_dec   = (const float*)d_in[7];
    const float* b_dec   = (const float*)d_in[8];
    float* out = (float*)d_out;
    int N = in_sizes[0] / 32;
    int E = in_sizes[1];

    char* w = (char*)d_ws;
    size_t o = 0;
    int* cursor = (int*)(w + o); o += (size_t)N * 4;   // doubles as cnt_in
    // region: pu (main, HBLK*32KB = 4 MB) or cnt_out (fallback, N*4)
    size_t region = (size_t)HBLK * 8192 * 4;
    if ((size_t)N * 4 > region) region = (size_t)N * 4;
    unsigned* pu  = (unsigned*)(w + o);
    int* cnt_out  = (int*)(w + o);
    o += region; o = (o + 255) & ~(size_t)255;
    float* inv_out = (float*)(w + o); o += (size_t)N * 4; o = (o + 255) & ~(size_t)255;
    float* inv_in  = (float*)(w + o); o += (size_t)N * 4; o = (o + 255) & ~(size_t)255;
    float* coef    = (float*)(w + o); o += 256;
    float* tsA     = (float*)(w + o); o += (size_t)N * 4; o = (o + 255) & ~(size_t)255;
    float* tsB     = (float*)(w + o); o += (size_t)N * 4; o = (o + 255) & ~(size_t)255;
    void* csr_mem  = (void*)(w + o);

    int nbl  = (N + 255) / 256;
    int nbl4 = (4 * N + 255) / 256;
    int ebl  = (E + 255) / 256;

    if (N <= 65536) {
        unsigned short* csr = (unsigned short*)csr_mem;
        prep_hist_kernel<<<HBLK + 1 + 31, 256, 0, stream>>>(src, W_embed, b_embed, Ws, bs,
                                                            W_dec, coef, cursor, pu, N, E);
        fill_kernel<<<ebl, 256, 0, stream>>>(src, dst, cursor, csr, E);
        z0_kernel<<<nbl, 256, 0, stream>>>(x, coef, pu, cursor, inv_out, inv_in, tsA, N);
        float* ta = tsA; float* tb = tsB;
        for (int k = 1; k <= 7; ++k) {
            prop_kernel<<<nbl4, 256, 0, stream>>>(ta, tb, inv_out, inv_in, cursor, csr, coef, k, N);
            float* tmp = ta; ta = tb; tb = tmp;
        }
        final_kernel<<<nbl4, 256, 0, stream>>>(ta, out, inv_in, cursor, csr, coef, b_dec, N);
    } else {
        int* csr = (int*)csr_mem;
        prep_kernel_i<<<128, 256, 0, stream>>>(W_embed, b_embed, Ws, bs, W_dec, coef, cursor, 2 * N);
        fill_kernel_i<<<ebl, 256, 0, stream>>>(src, dst, cnt_out, cursor, csr, E);
        z0_kernel_i<<<nbl, 256, 0, stream>>>(x, coef, cnt_out, cursor, inv_out, inv_in, tsA, N);
        float* ta = tsA; float* tb = tsB;
        for (int k = 1; k <= 7; ++k) {
            prop_kernel_i<<<nbl, 256, 0, stream>>>(ta, tb, inv_out, inv_in, cursor, csr, coef, k, N);
            float* tmp = ta; ta = tb; tb = tmp;
        }
        final_kernel_i<<<nbl, 256, 0, stream>>>(ta, out, inv_in, cursor, csr, coef, b_dec, N);
    }
}

// Round 14
// 114.860 us; speedup vs baseline: 2.0343x; 1.0397x over previous
//
#include <hip/hip_runtime.h>

// GNN collapse: out = A^8 (x · w_in) + sum_l gamma_l A^{8-l} 1 + b_dec
// where A = D_in^-1/2 Adj D_out^-1/2 (scalar field propagation).
//
// Lessons: coop grid.sync 10x worse than small launches (R5). Device-scope
// atomic/scattered-store memory-side ops cost ~28 B HBM traffic each at
// ~30 Gops/s regardless of occupancy>~25% (R2/R4/R7/R10) -> minimize op
// COUNT. Static __shared__ charged grid-wide (R8). Owner-computes needs
// block-parallelism AND per-thread ILP (R9/R10). Zero-global-atomic fills
// lose: range-split scans edges NRx (R11), full-node LDS cursors kill
// occupancy (R12). CSR build floor = 1 atomic + 1 store per edge (R10).
// R14: z0 fused into fill dispatch (independent roles, trivial LDS);
// inv_in computed on the fly from cursor (saves array + z0 pass).

#define PAD 48     // max in-degree bound; 48 ushorts = 96 B row
#define HS 32      // histogram slices
#define HR 4       // histogram node ranges (16384 nodes, 32 KB LDS each)
#define HBLK (HS * HR)

// ---- prep + src-histogram: one dispatch ----
// blocks [0,HBLK): owner-computes src histogram. Block b: slice q=b>>2,
//   range r=b&3 (nodes [r*16384,(r+1)*16384)). LDS = 8192 uints = 16384
//   packed ushort counters. pu[b*8192 + i] privately owned -> plain stores.
// block HBLK: coefficient chain. blocks > HBLK: zero cursor.
// coef[0..8] = gamma_0..gamma_8, coef[16..47] = w_in[0..31]
__global__ __launch_bounds__(256) void prep_hist_kernel(
        const int* __restrict__ src,
        const float* __restrict__ W_embed, const float* __restrict__ b_embed,
        const float* __restrict__ Ws, const float* __restrict__ bs,
        const float* __restrict__ W_dec, float* __restrict__ coef,
        int* __restrict__ cursor, unsigned* __restrict__ pu, int N, int E) {
    __shared__ unsigned lds[8192];   // 32 KB
    int b = blockIdx.x;
    if (b < HBLK) {
        int q = b >> 2, r = b & 3;
        for (int i = threadIdx.x; i < 8192; i += 256) lds[i] = 0;
        __syncthreads();
        int base = r << 14;
        int per = ((E + HS - 1) / HS + 3) & ~3;      // slice length, 4-aligned
        int e0 = q * per;
        int e1 = e0 + per; if (e1 > E) e1 = E;
        if (e0 < e1) {
            const int4* p4 = (const int4*)(src + e0);
            int m4 = (e1 - e0) >> 2;
            for (int i = threadIdx.x; i < m4; i += 256) {
                int4 v = p4[i];
                int t;
                t = v.x - base; if ((unsigned)t < 16384u) atomicAdd(&lds[t >> 1], 1u << ((t & 1) * 16));
                t = v.y - base; if ((unsigned)t < 16384u) atomicAdd(&lds[t >> 1], 1u << ((t & 1) * 16));
                t = v.z - base; if ((unsigned)t < 16384u) atomicAdd(&lds[t >> 1], 1u << ((t & 1) * 16));
                t = v.w - base; if ((unsigned)t < 16384u) atomicAdd(&lds[t >> 1], 1u << ((t & 1) * 16));
            }
            for (int e = e0 + (m4 << 2) + threadIdx.x; e < e1; e += 256) {
                int t = src[e] - base;
                if ((unsigned)t < 16384u) atomicAdd(&lds[t >> 1], 1u << ((t & 1) * 16));
            }
        }
        __syncthreads();
        unsigned* outp = pu + (size_t)b * 8192;
        for (int i = threadIdx.x; i < 8192; i += 256) outp[i] = lds[i];
    } else if (b == HBLK) {
        __shared__ float shv[64];
        __shared__ float shg[9];
        int i = threadIdx.x;
        if (i < 64) shv[i] = W_dec[i];
        __syncthreads();
        for (int l = 7; l >= 0; --l) {
            float a = 0.f;
            if (i < 64) {
                float p = bs[l * 64 + i] * shv[i];
                for (int d = 32; d; d >>= 1) p += __shfl_xor(p, d);
                if (i == 0) shg[l + 1] = p;
                const float* Wrow = Ws + l * 4096 + i * 64;
                for (int j = 0; j < 64; ++j) a += Wrow[j] * shv[j];
            }
            __syncthreads();
            if (i < 64) shv[i] = a;
            __syncthreads();
        }
        if (i < 64) {
            float p = b_embed[i] * shv[i];
            for (int d = 32; d; d >>= 1) p += __shfl_xor(p, d);
            if (i == 0) shg[0] = p;
        }
        __syncthreads();
        if (i < 32) {
            float a = 0.f;
            const float* Wr = W_embed + i * 64;
            for (int j = 0; j < 64; ++j) a += Wr[j] * shv[j];
            coef[16 + i] = a;
        }
        if (i < 9) coef[i] = shg[i];
    } else {
        int g = (b - HBLK - 1) * 256 + threadIdx.x;
        int stride = (gridDim.x - HBLK - 1) * 256;
        for (int i = g; i < N; i += stride) cursor[i] = 0;
    }
}

// ---- fused fill + z0 (one dispatch; independent roles) ----
// blocks [0,EB): fill — 1 edge/thread, returning atomicAdd on cursor[dst]
//   doubles as in-degree count and csr slot.
// blocks [EB,EB+NB): z0 — ts0[n] = inv_out[n]*(x[n]·w_in + gamma_0),
//   inv_out from src-histogram partials. No dependence on fill.
__global__ __launch_bounds__(256) void fill_z0_kernel(
        const int* __restrict__ src, const int* __restrict__ dst,
        int* __restrict__ cursor, unsigned short* __restrict__ csr,
        const float* __restrict__ x, const float* __restrict__ coef,
        const unsigned* __restrict__ pu, float* __restrict__ inv_out,
        float* __restrict__ ts0, int EB, int N, int E) {
    __shared__ float w[33];   // 132 B — no occupancy impact
    int b = blockIdx.x;
    if (b < EB) {
        int i = b * 256 + threadIdx.x;
        if (i >= E) return;
        int s = src[i], d = dst[i];
        int p = atomicAdd(&cursor[d], 1);
        if (p < PAD) csr[(size_t)d * PAD + p] = (unsigned short)s;
    } else {
        if (threadIdx.x < 32) w[threadIdx.x] = coef[16 + threadIdx.x];
        if (threadIdx.x == 32) w[32] = coef[0];
        __syncthreads();
        int n = (b - EB) * 256 + threadIdx.x;
        if (n >= N) return;
        const float4* xr = (const float4*)(x + (size_t)n * 32);
        float acc = 0.f;
#pragma unroll
        for (int q = 0; q < 8; ++q) {
            float4 vv = xr[q];
            acc += vv.x * w[q * 4] + vv.y * w[q * 4 + 1] + vv.z * w[q * 4 + 2] + vv.w * w[q * 4 + 3];
        }
        int r = n >> 14, j = (n & 16383) >> 1, sh = (n & 1) * 16;
        int co = 0;
#pragma unroll
        for (int q = 0; q < HS; ++q)
            co += (pu[(size_t)((q << 2) | r) * 8192 + j] >> sh) & 0xFFFF;
        if (co < 1) co = 1;
        float io = rsqrtf((float)co);
        inv_out[n] = io;
        ts0[n] = io * (acc + w[32]);
    }
}

// ---- 4-lane-per-node gather, branchless index loads ----
// All 3 uint2 index loads issued up-front (rows PAD-padded; garbage slots
// read valid workspace memory and are predicated off at the accumulate).
__device__ __forceinline__ float quad_gather(const unsigned short* __restrict__ row,
                                             const float* __restrict__ ta,
                                             int c, int sub) {
    int e0 = sub * 4;
    uint2 v0 = *(const uint2*)(row + e0);        // slots e0..e0+3
    uint2 v1 = *(const uint2*)(row + e0 + 16);   // slots e0+16..
    uint2 v2 = *(const uint2*)(row + e0 + 32);   // slots e0+32..
    float acc = 0.f;
#define ACC4(v, eb)                                                        \
    {                                                                      \
        unsigned a0 = (v).x & 0xFFFFu, a1 = (v).x >> 16;                   \
        unsigned a2 = (v).y & 0xFFFFu, a3 = (v).y >> 16;                   \
        if ((eb) + 0 < c) acc += ta[a0];                                   \
        if ((eb) + 1 < c) acc += ta[a1];                                   \
        if ((eb) + 2 < c) acc += ta[a2];                                   \
        if ((eb) + 3 < c) acc += ta[a3];                                   \
    }
    ACC4(v0, e0)
    ACC4(v1, e0 + 16)
    ACC4(v2, e0 + 32)
#undef ACC4
    return acc;
}

// ts_out[n] = inv_out[n] * (rsqrt(deg_in) * gather + coef[k]);  4 thr/node
__global__ __launch_bounds__(256) void prop_kernel(
        const float* __restrict__ ts_in, float* __restrict__ ts_out,
        const float* __restrict__ inv_out,
        const int* __restrict__ cursor, const unsigned short* __restrict__ csr,
        const float* __restrict__ coef, int k, int N) {
    int tid = blockIdx.x * 256 + threadIdx.x;
    int n = tid >> 2, sub = tid & 3;
    if (n >= N) return;
    int cr = cursor[n];
    int c = cr > PAD ? PAD : cr;
    float acc = quad_gather(csr + (size_t)n * PAD, ts_in, c, sub);
    acc += __shfl_xor(acc, 1);
    acc += __shfl_xor(acc, 2);
    if (sub == 0) {
        float ii = rsqrtf((float)(cr < 1 ? 1 : cr));
        ts_out[n] = inv_out[n] * (ii * acc + coef[k]);
    }
}

// out[n] = rsqrt(deg_in) * gather + coef[8] + b_dec;  4 threads per node
__global__ __launch_bounds__(256) void final_kernel(
        const float* __restrict__ ts_in, float* __restrict__ out,
        const int* __restrict__ cursor,
        const unsigned short* __restrict__ csr, const float* __restrict__ coef,
        const float* __restrict__ b_dec, int N) {
    int tid = blockIdx.x * 256 + threadIdx.x;
    int n = tid >> 2, sub = tid & 3;
    if (n >= N) return;
    int cr = cursor[n];
    int c = cr > PAD ? PAD : cr;
    float acc = quad_gather(csr + (size_t)n * PAD, ts_in, c, sub);
    acc += __shfl_xor(acc, 1);
    acc += __shfl_xor(acc, 2);
    if (sub == 0) {
        float ii = rsqrtf((float)(cr < 1 ? 1 : cr));
        out[n] = ii * acc + coef[8] + b_dec[0];
    }
}

// ---- int-id fallback (N > 65536): R7 structure, int CSR, atomic counters ----
__global__ __launch_bounds__(256) void prep_kernel_i(
        const float* __restrict__ W_embed, const float* __restrict__ b_embed,
        const float* __restrict__ Ws, const float* __restrict__ bs,
        const float* __restrict__ W_dec, float* __restrict__ coef,
        int* __restrict__ cnt, int NZ) {
    int g = blockIdx.x * 256 + threadIdx.x;
    for (int i = g; i < NZ; i += gridDim.x * 256) cnt[i] = 0;
    if (blockIdx.x == 0) {
        __shared__ float shv[64];
        __shared__ float shg[9];
        int i = threadIdx.x;
        if (i < 64) shv[i] = W_dec[i];
        __syncthreads();
        for (int l = 7; l >= 0; --l) {
            float a = 0.f;
            if (i < 64) {
                float p = bs[l * 64 + i] * shv[i];
                for (int d = 32; d; d >>= 1) p += __shfl_xor(p, d);
                if (i == 0) shg[l + 1] = p;
                const float* Wrow = Ws + l * 4096 + i * 64;
                for (int j = 0; j < 64; ++j) a += Wrow[j] * shv[j];
            }
            __syncthreads();
            if (i < 64) shv[i] = a;
            __syncthreads();
        }
        if (i < 64) {
            float p = b_embed[i] * shv[i];
            for (int d = 32; d; d >>= 1) p += __shfl_xor(p, d);
            if (i == 0) shg[0] = p;
        }
        __syncthreads();
        if (i < 32) {
            float a = 0.f;
            const float* Wr = W_embed + i * 64;
            for (int j = 0; j < 64; ++j) a += Wr[j] * shv[j];
            coef[16 + i] = a;
        }
        if (i < 9) coef[i] = shg[i];
    }
}

__global__ __launch_bounds__(256) void fill_kernel_i(
        const int* __restrict__ src, const int* __restrict__ dst,
        int* __restrict__ cnt_out, int* __restrict__ cursor,
        int* __restrict__ csr, int E) {
    int i = blockIdx.x * 256 + threadIdx.x;
    if (i >= E) return;
    int s = src[i], d = dst[i];
    atomicAdd(&cnt_out[s], 1);
    int p = atomicAdd(&cursor[d], 1);
    if (p < PAD) csr[(size_t)d * PAD + p] = s;
}

__global__ __launch_bounds__(256) void z0_kernel_i(
        const float* __restrict__ x, const float* __restrict__ coef,
        const int* __restrict__ cnt_out,
        float* __restrict__ inv_out, float* __restrict__ ts0, int N) {
    __shared__ float w[33];
    if (threadIdx.x < 32) w[threadIdx.x] = coef[16 + threadIdx.x];
    if (threadIdx.x == 32) w[32] = coef[0];
    __syncthreads();
    int n = blockIdx.x * 256 + threadIdx.x;
    if (n >= N) return;
    const float4* xr = (const float4*)(x + (size_t)n * 32);
    float acc = 0.f;
#pragma unroll
    for (int q = 0; q < 8; ++q) {
        float4 vv = xr[q];
        acc += vv.x * w[q * 4] + vv.y * w[q * 4 + 1] + vv.z * w[q * 4 + 2] + vv.w * w[q * 4 + 3];
    }
    int co = cnt_out[n]; if (co < 1) co = 1;
    float io = rsqrtf((float)co);
    inv_out[n] = io;
    ts0[n] = io * (acc + w[32]);
}

__global__ __launch_bounds__(256) void prop_kernel_i(
        const float* __restrict__ ts_in, float* __restrict__ ts_out,
        const float* __restrict__ inv_out,
        const int* __restrict__ cursor, const int* __restrict__ csr,
        const float* __restrict__ coef, int k, int N) {
    int n = blockIdx.x * 256 + threadIdx.x;
    if (n >= N) return;
    int cr = cursor[n];
    int c = cr > PAD ? PAD : cr;
    const int* row = csr + (size_t)n * PAD;
    float acc = 0.f;
    for (int e = 0; e < c; ++e) acc += ts_in[row[e]];
    float ii = rsqrtf((float)(cr < 1 ? 1 : cr));
    ts_out[n] = inv_out[n] * (ii * acc + coef[k]);
}

__global__ __launch_bounds__(256) void final_kernel_i(
        const float* __restrict__ ts_in, float* __restrict__ out,
        const int* __restrict__ cursor,
        const int* __restrict__ csr, const float* __restrict__ coef,
        const float* __restrict__ b_dec, int N) {
    int n = blockIdx.x * 256 + threadIdx.x;
    if (n >= N) return;
    int cr = cursor[n];
    int c = cr > PAD ? PAD : cr;
    const int* row = csr + (size_t)n * PAD;
    float acc = 0.f;
    for (int e = 0; e < c; ++e) acc += ts_in[row[e]];
    float ii = rsqrtf((float)(cr < 1 ? 1 : cr));
    out[n] = ii * acc + coef[8] + b_dec[0];
}

extern "C" void kernel_launch(void* const* d_in, const int* in_sizes, int n_in,
                              void* d_out, int out_size, void* d_ws, size_t ws_size,
                              hipStream_t stream) {
    const float* x       = (const float*)d_in[0];
    const int*   src     = (const int*)d_in[1];
    const int*   dst     = (const int*)d_in[2];
    const float* W_embed = (const float*)d_in[3];
    const float* b_embed = (const float*)d_in[4];
    const float* Ws      = (const float*)d_in[5];
    const float* bs      = (const float*)d_in[6];
    const float* W_dec   = (const float*)d_in[7];
    const float* b_dec   = (const float*)d_in[8];
    float* out = (float*)d_out;
    int N = in_sizes[0] / 32;
    int E = in_sizes[1];

    char* w = (char*)d_ws;
    size_t o = 0;
    int* cursor = (int*)(w + o); o += (size_t)N * 4;   // doubles as cnt_in
    // region: pu (main, HBLK*32KB = 4 MB) or cnt_out (fallback, N*4)
    size_t region = (size_t)HBLK * 8192 * 4;
    if ((size_t)N * 4 > region) region = (size_t)N * 4;
    unsigned* pu  = (unsigned*)(w + o);
    int* cnt_out  = (int*)(w + o);
    o += region; o = (o + 255) & ~(size_t)255;
    float* inv_out = (float*)(w + o); o += (size_t)N * 4; o = (o + 255) & ~(size_t)255;
    float* coef    = (float*)(w + o); o += 256;
    float* tsA     = (float*)(w + o); o += (size_t)N * 4; o = (o + 255) & ~(size_t)255;
    float* tsB     = (float*)(w + o); o += (size_t)N * 4; o = (o + 255) & ~(size_t)255;
    void* csr_mem  = (void*)(w + o);

    int nbl  = (N + 255) / 256;
    int nbl4 = (4 * N + 255) / 256;
    int ebl  = (E + 255) / 256;

    if (N <= 65536) {
        unsigned short* csr = (unsigned short*)csr_mem;
        prep_hist_kernel<<<HBLK + 1 + 31, 256, 0, stream>>>(src, W_embed, b_embed, Ws, bs,
                                                            W_dec, coef, cursor, pu, N, E);
        fill_z0_kernel<<<ebl + nbl, 256, 0, stream>>>(src, dst, cursor, csr,
                                                      x, coef, pu, inv_out, tsA, ebl, N, E);
        float* ta = tsA; float* tb = tsB;
        for (int k = 1; k <= 7; ++k) {
            prop_kernel<<<nbl4, 256, 0, stream>>>(ta, tb, inv_out, cursor, csr, coef, k, N);
            float* tmp = ta; ta = tb; tb = tmp;
        }
        final_kernel<<<nbl4, 256, 0, stream>>>(ta, out, cursor, csr, coef, b_dec, N);
    } else {
        int* csr = (int*)csr_mem;
        prep_kernel_i<<<128, 256, 0, stream>>>(W_embed, b_embed, Ws, bs, W_dec, coef, cursor, 2 * N);
        fill_kernel_i<<<ebl, 256, 0, stream>>>(src, dst, cnt_out, cursor, csr, E);
        z0_kernel_i<<<nbl, 256, 0, stream>>>(x, coef, cnt_out, inv_out, tsA, N);
        float* ta = tsA; float* tb = tsB;
        for (int k = 1; k <= 7; ++k) {
            prop_kernel_i<<<nbl, 256, 0, stream>>>(ta, tb, inv_out, cursor, csr, coef, k, N);
            float* tmp = ta; ta = tb; tb = tmp;
        }
        final_kernel_i<<<nbl, 256, 0, stream>>>(ta, out, cursor, csr, coef, b_dec, N);
    }
}